// Round 17
// baseline (175.633 us; speedup 1.0000x reference)
//
#include <hip/hip_runtime.h>
#include <hip/hip_bf16.h>
#include <stdint.h>
#include <stddef.h>

#define B_ 4
#define L_ 1024
#define D_ 1024
#define H_ 16
#define HD_ 64
#define NROW 65536      // B*L*H
#define QE_LD 132       // qE row stride (bf16 elems); cols 0..127 from GEMM, 128 from flash prologue
#define EV_LD 192       // EvT row stride (= out2 MFMA K, 6 k-tiles of 32)
#define T_STR 200       // epilogue T row stride in LDS (u16; pad kills conflicts)

typedef __attribute__((ext_vector_type(8))) short bf16x8;
typedef __attribute__((ext_vector_type(4))) float f32x4;
typedef __attribute__((ext_vector_type(4))) unsigned short u16x4;

__device__ __forceinline__ float bf2f(unsigned short u) {
  union { unsigned int i; float f; } v; v.i = ((unsigned int)u) << 16; return v.f;
}
__device__ __forceinline__ unsigned short f2bf(float f) {
  union { float f; unsigned int i; } v; v.f = f;
  return (unsigned short)((v.i + 0x7fffu + ((v.i >> 16) & 1u)) >> 16);
}
__device__ __forceinline__ unsigned short f2bfrn(float f) {
  __hip_bfloat16 h = __float2bfloat16(f);
  return *reinterpret_cast<unsigned short*>(&h);
}
__device__ __forceinline__ void async16(const void* g, void* l) {
  __builtin_amdgcn_global_load_lds(
      (const __attribute__((address_space(1))) unsigned int*)g,
      (__attribute__((address_space(3))) unsigned int*)l, 16, 0, 0);
}

// ---------------------------------------------------------------------------
// f32 -> bf16 convert, 7 tensors + Ek/Ev padding, one dispatch
// ---------------------------------------------------------------------------
struct ConvArgs {
  const float* s[7]; unsigned short* d[7]; int n4[7];
  const float* ek; const float* ev;
  unsigned short* ekp; unsigned short* evtp;
};

__global__ __launch_bounds__(256) void f32_to_bf16_multi(ConvArgs a) {
  const int y = blockIdx.y;
  if (y == 7) {
    int i = blockIdx.x * 256 + threadIdx.x;
    if (i < 256 * 64) {
      int r = i >> 6, dd = i & 63;
      a.ekp[i] = (r < 129) ? f2bf(a.ek[r * 64 + dd]) : (unsigned short)0;
    }
    if (i < 128 * EV_LD) {
      int dd = i / EV_LD, r = i - dd * EV_LD;
      a.evtp[i] = (dd < 64 && r < 129) ? f2bf(a.ev[r * 64 + dd]) : (unsigned short)0;
    }
    return;
  }
  const float* s = a.s[y];
  unsigned short* d = a.d[y];
  const int n4 = a.n4[y];
  int i = blockIdx.x * 256 + threadIdx.x;
  int stride = gridDim.x * 256;
  for (; i < n4; i += stride) {
    float4 v = ((const float4*)s)[i];
    u16x4 o;
    o[0] = f2bf(v.x); o[1] = f2bf(v.y); o[2] = f2bf(v.z); o[3] = f2bf(v.w);
    ((u16x4*)d)[i] = o;
  }
}

// ---------------------------------------------------------------------------
// GEMM: C[M,N] = A[M,K] * Bt[N,K]^T (+bias) ; bf16 in, f32 acc.
// Tile (MI*32)x128, BK=32, 4 waves, chunk-swizzled LDS, global_load_lds x16.
// z-batched (blockIdx.z selects pointer set). VPT: for z==2 the epilogue
// writes C transposed as vpT (B,H,HD,L) directly.
// ---------------------------------------------------------------------------
struct Gemm3 {
  const unsigned short* A[3];
  const unsigned short* Bt[3];
  const float* bias[3];
  void* C[3];
};

template<int MI, bool OBF16, bool BIAS, bool VPT>
__global__ __launch_bounds__(256, 8 / MI) void gemm_bt(Gemm3 ga, int lda, int ldb, int ldc,
                                                       int Ncut, int ktiles) {
  constexpr int BM = MI * 32;
  __shared__ unsigned short Al[2][BM * 32];
  __shared__ unsigned short Bl[2][128 * 32];
  const unsigned short* A = ga.A[blockIdx.z];
  const unsigned short* Bt = ga.Bt[blockIdx.z];
  const float* bias = ga.bias[blockIdx.z];
  void* Cv = ga.C[blockIdx.z];
  const int tid = threadIdx.x;
  const int w = tid >> 6, l = tid & 63;
  const int l15 = l & 15, lg = l >> 4;
  const int row0 = blockIdx.x * BM, col0 = blockIdx.y * 128;
  const int wm = (w >> 1) * (MI * 16), wn = (w & 1) * 64;

  f32x4 acc[MI][4];
#pragma unroll
  for (int i = 0; i < MI; ++i)
#pragma unroll
    for (int j = 0; j < 4; ++j) acc[i][j] = {0.f, 0.f, 0.f, 0.f};

  auto stage = [&](int buf, int kt) {
#pragma unroll
    for (int i = 0; i < MI / 2; ++i) {
      int p = (i * 4 + w) * 1024 + l * 16;   // byte offset within A tile
      int m = p >> 6;                        // tile-local row (64B rows)
      int clog = (l & 3) ^ ((m >> 1) & 3);   // logical k-chunk for this slot
      async16(A + (size_t)(row0 + m) * lda + kt * 32 + clog * 8,
              (char*)&Al[buf][0] + (i * 4 + w) * 1024);
    }
#pragma unroll
    for (int i = 0; i < 2; ++i) {
      int p = (i * 4 + w) * 1024 + l * 16;
      int m = p >> 6;
      int clog = (l & 3) ^ ((m >> 1) & 3);
      async16(Bt + (size_t)(col0 + m) * ldb + kt * 32 + clog * 8,
              (char*)&Bl[buf][0] + (i * 4 + w) * 1024);
    }
  };

  stage(0, 0);
  __syncthreads();
  for (int kt = 0; kt < ktiles; ++kt) {
    int cur = kt & 1;
    if (kt + 1 < ktiles) stage(cur ^ 1, kt + 1);
    bf16x8 af[MI], bfr[4];
#pragma unroll
    for (int mi = 0; mi < MI; ++mi) {
      int m = wm + mi * 16 + l15;
      af[mi] = *(const bf16x8*)&Al[cur][m * 32 + ((lg ^ ((m >> 1) & 3)) << 3)];
    }
#pragma unroll
    for (int ni = 0; ni < 4; ++ni) {
      int n = wn + ni * 16 + l15;
      bfr[ni] = *(const bf16x8*)&Bl[cur][n * 32 + ((lg ^ ((n >> 1) & 3)) << 3)];
    }
#pragma unroll
    for (int mi = 0; mi < MI; ++mi)
#pragma unroll
      for (int ni = 0; ni < 4; ++ni)
        acc[mi][ni] = __builtin_amdgcn_mfma_f32_16x16x32_bf16(af[mi], bfr[ni], acc[mi][ni], 0, 0, 0);
    __syncthreads();
  }

  if (VPT && blockIdx.z == 2) {
    // write C transposed: col -> (h,d), row -> (b,l); 4 rows = contiguous u16x4
    unsigned short* vpT = (unsigned short*)Cv;
#pragma unroll
    for (int ni = 0; ni < 4; ++ni) {
      int col = col0 + wn + ni * 16 + l15;
      float bv = BIAS ? bias[col] : 0.f;
#pragma unroll
      for (int mi = 0; mi < MI; ++mi) {
        int rowb = row0 + wm + mi * 16 + lg * 4;
        int bb = rowb >> 10, lrow = rowb & 1023;
        u16x4 o;
#pragma unroll
        for (int r = 0; r < 4; ++r) o[r] = f2bf(acc[mi][ni][r] + bv);
        *(u16x4*)(vpT + ((size_t)((bb * H_ + (col >> 6)) * HD_ + (col & 63))) * L_ + lrow) = o;
      }
    }
    return;
  }

#pragma unroll
  for (int ni = 0; ni < 4; ++ni) {
    int col = col0 + wn + ni * 16 + l15;
    if (col < Ncut) {
      float bv = BIAS ? bias[col] : 0.f;
#pragma unroll
      for (int mi = 0; mi < MI; ++mi) {
        int rowb = row0 + wm + mi * 16 + lg * 4;
#pragma unroll
        for (int r = 0; r < 4; ++r) {
          float v = acc[mi][ni][r] + bv;
          size_t off = (size_t)(rowb + r) * ldc + col;
          if (OBF16) ((unsigned short*)Cv)[off] = f2bf(v);
          else       ((float*)Cv)[off] = v;
        }
      }
    }
  }
}

// ---------------------------------------------------------------------------
// Fused flash attention + relative logits + FULL out2 (T @ EvT) in epilogue.
// Swapped QK^T (lane owns q-row), log2-domain softmax, defer-max THR=8.
// K staged in LDS (double-buffered, swizzled); V read DIRECTLY from global
// (L2-resident at S=1024 -- staging it was pure overhead; m169 pattern).
// V fragments issued right after QK^T so L2 latency hides under softmax.
// qe128 computed in prologue and stored to qerow[128] (unconditional gather).
// Grid: 1024 linear blocks, bh = bid&63 (XCD locality), qt = bid>>6.
// ---------------------------------------------------------------------------
__global__ __launch_bounds__(256, 3) void flash_fwd_k(
    const unsigned short* __restrict__ qp, const unsigned short* __restrict__ kp,
    const unsigned short* __restrict__ vpT, unsigned short* __restrict__ qE,
    const unsigned short* __restrict__ Ekp, const unsigned short* __restrict__ EvTp,
    unsigned short* __restrict__ tmp) {
  __shared__ __align__(16) char smem[25600];   // Kl 16K + Pl 8K; epilogue T 25.6K
  unsigned short (*Kl)[4096] = (unsigned short (*)[4096])smem;
  const int tid = threadIdx.x, w = tid >> 6, l = tid & 63;
  unsigned short* Plw = (unsigned short*)(smem + 16384) + w * 1024;
  const int l15 = l & 15, lg = l >> 4;
  const int bid = blockIdx.x;
  const int bh = bid & 63, qt = bid >> 6;
  const int b = bh >> 4, h = bh & 15;
  const int qw = qt * 64 + w * 16;
  const int q_lane = qw + l15;                 // this lane's q row
  const int rowbase = (b * L_ + qw) * H_ + h;
  const int rowi_lane = rowbase + l15 * H_;
  const unsigned short* vbase0 = vpT + ((size_t)((b * H_ + h) * HD_)) * L_;
  constexpr float C1 = 0.125f * 1.44269504f;   // scale * log2(e)

  // Q fragments (B-operand): col = q = qw + l15, d-chunk = ks*32 + lg*8
  bf16x8 qf[2];
  {
    const unsigned short* qrp = qp + (size_t)rowi_lane * HD_;
#pragma unroll
    for (int ks = 0; ks < 2; ++ks) qf[ks] = *(const bf16x8*)(qrp + ks * 32 + lg * 8);
  }
  unsigned short* qerow = qE + (size_t)rowi_lane * QE_LD;
  const float qe0L = bf2f(qerow[0]) * C1;
  // qe128 = qp[row] . Ek[128] : per-lane 16-elem partial + xor16/xor32 reduce.
  float qe128L;
  {
    const unsigned short* ek128 = Ekp + 128 * 64;
    float dot = 0.f;
#pragma unroll
    for (int ks = 0; ks < 2; ++ks) {
      const unsigned short* ep = ek128 + ks * 32 + lg * 8;
#pragma unroll
      for (int e = 0; e < 8; ++e)
        dot += bf2f((unsigned short)qf[ks][e]) * bf2f(ep[e]);
    }
    dot += __shfl_xor(dot, 16);
    dot += __shfl_xor(dot, 32);
    qerow[128] = f2bf(dot);      // same-thread store; read later by this lane only
    qe128L = dot * C1;
  }

  f32x4 O[4];
#pragma unroll
  for (int nd = 0; nd < 4; ++nd) O[nd] = {0.f, 0.f, 0.f, 0.f};
  float mrow = -1e30f, lrow = 0.f, t0row = 0.f;   // mrow in log2-units

  // band state (static-indexed register arrays)
  u16x4 pks0[4], pks1[4], pks2[4];
  float mu0 = -1e30f, mu1 = -1e30f, mu2 = -1e30f;
  {
    u16x4 z4 = {0, 0, 0, 0};
#pragma unroll
    for (int ni = 0; ni < 4; ++ni) { pks0[ni] = z4; pks1[ni] = z4; pks2[ni] = z4; }
  }

  auto stageK = [&](int buf, int kt) {
#pragma unroll
    for (int i = 0; i < 2; ++i) {
      int p = (i * 4 + w) * 1024 + l * 16;  // byte in 8KB tile (rows = 128B)
      int row = p >> 7;
      int clog = (l & 7) ^ (row & 7);
      async16(kp + ((size_t)((b * L_ + kt * 64 + row) * H_ + h)) * HD_ + clog * 8,
              (char*)&Kl[buf][0] + (i * 4 + w) * 1024);
    }
  };

  stageK(0, 0);
  __syncthreads();

  for (int kt = 0; kt < 16; ++kt) {
    int cur = kt & 1;
    if (kt + 1 < 16) stageK(cur ^ 1, kt + 1);

    // S^T = K * Q^T: lane col = q (l15), rows = k-local (ni*16 + lg*4 + r)
    f32x4 S[4];
#pragma unroll
    for (int ni = 0; ni < 4; ++ni) S[ni] = {0.f, 0.f, 0.f, 0.f};
#pragma unroll
    for (int ks = 0; ks < 2; ++ks) {
      bf16x8 kf[4];
#pragma unroll
      for (int ni = 0; ni < 4; ++ni) {
        int kk = ni * 16 + l15;
        kf[ni] = *(const bf16x8*)&Kl[cur][kk * 64 + (((ks * 4 + lg) ^ (kk & 7)) << 3)];
      }
#pragma unroll
      for (int ni = 0; ni < 4; ++ni)
        S[ni] = __builtin_amdgcn_mfma_f32_16x16x32_bf16(kf[ni], qf[ks], S[ni], 0, 0, 0);
    }

    // issue V fragment loads NOW (global, L2-resident) -- latency hides
    // under the softmax VALU chain below.
    bf16x8 vg[2][4];
    {
      const unsigned short* vb = vbase0 + kt * 64;
#pragma unroll
      for (int ks = 0; ks < 2; ++ks)
#pragma unroll
        for (int nd = 0; nd < 4; ++nd)
          vg[ks][nd] = *(const bf16x8*)(vb + (size_t)(nd * 16 + l15) * L_ + (ks * 4 + lg) * 8);
    }

    const int cls = (kt <= qt - 2) ? 0 : ((kt >= qt + 2) ? 2 : 1);
    const int based = kt * 64 - q_lane;

    // logits in log2 domain (band: unconditional clamp-indexed gather [0..128])
    if (cls == 1) {
#pragma unroll
      for (int ni = 0; ni < 4; ++ni)
#pragma unroll
        for (int r = 0; r < 4; ++r) {
          int delta = based + ni * 16 + lg * 4 + r;
          int idx = min(max(delta, -64), 64) + 64;
          S[ni][r] = S[ni][r] * C1 + bf2f(qerow[idx]) * C1;
        }
    } else {
      float qeL = (cls == 0) ? qe0L : qe128L;
#pragma unroll
      for (int ni = 0; ni < 4; ++ni)
#pragma unroll
        for (int r = 0; r < 4; ++r) S[ni][r] = S[ni][r] * C1 + qeL;
    }

    // row max: reg tree + 2 shuffles
    float x0 = fmaxf(fmaxf(S[0][0], S[0][1]), fmaxf(S[0][2], S[0][3]));
    float x1 = fmaxf(fmaxf(S[1][0], S[1][1]), fmaxf(S[1][2], S[1][3]));
    float x2 = fmaxf(fmaxf(S[2][0], S[2][1]), fmaxf(S[2][2], S[2][3]));
    float x3 = fmaxf(fmaxf(S[3][0], S[3][1]), fmaxf(S[3][2], S[3][3]));
    float pmax = fmaxf(fmaxf(x0, x1), fmaxf(x2, x3));
    pmax = fmaxf(pmax, __shfl_xor(pmax, 16));
    pmax = fmaxf(pmax, __shfl_xor(pmax, 32));

    // defer-max (THR = 8 nats = 11.54 log2-units)
    float a = 1.f;
    if (!__all(pmax <= mrow + 11.54f)) {
      float mnew = fmaxf(mrow, pmax);
      a = __builtin_amdgcn_exp2f(mrow - mnew);
      mrow = mnew;
      float aq0 = __shfl(a, lg * 4 + 0);
      float aq1 = __shfl(a, lg * 4 + 1);
      float aq2 = __shfl(a, lg * 4 + 2);
      float aq3 = __shfl(a, lg * 4 + 3);
#pragma unroll
      for (int nd = 0; nd < 4; ++nd) {
        O[nd][0] *= aq0; O[nd][1] *= aq1; O[nd][2] *= aq2; O[nd][3] *= aq3;
      }
    }

    // p = exp2(sL - mL)
#pragma unroll
    for (int ni = 0; ni < 4; ++ni)
#pragma unroll
      for (int r = 0; r < 4; ++r)
        S[ni][r] = __builtin_amdgcn_exp2f(S[ni][r] - mrow);

    float s0 = (S[0][0] + S[0][1]) + (S[0][2] + S[0][3]);
    float s1 = (S[1][0] + S[1][1]) + (S[1][2] + S[1][3]);
    float s2 = (S[2][0] + S[2][1]) + (S[2][2] + S[2][3]);
    float s3 = (S[3][0] + S[3][1]) + (S[3][2] + S[3][3]);
    float ps = (s0 + s1) + (s2 + s3);
    ps += __shfl_xor(ps, 16);
    ps += __shfl_xor(ps, 32);
    lrow = lrow * a + ps;

    if (cls == 0) {
      t0row = t0row * a + ps;
    } else if (cls == 2) {
      t0row = t0row * a;
    } else if (kt == qt - 1) {
      float p0 = 0.f;
#pragma unroll
      for (int ni = 0; ni < 4; ++ni)
#pragma unroll
        for (int r = 0; r < 4; ++r)
          if (based + ni * 16 + lg * 4 + r <= -64) p0 += S[ni][r];
      p0 += __shfl_xor(p0, 16);
      p0 += __shfl_xor(p0, 32);
      t0row = t0row * a + p0;
    } else {
      t0row = t0row * a;
    }

    // pack p to bf16; write Pl (per-wave, swizzled); save band tiles to regs
    u16x4 pcur[4];
#pragma unroll
    for (int ni = 0; ni < 4; ++ni) {
      u16x4 pk;
#pragma unroll
      for (int r = 0; r < 4; ++r) pk[r] = f2bfrn(S[ni][r]);
      pcur[ni] = pk;
      int slot = (ni * 2 + (lg >> 1)) ^ (l15 & 7);
      int addr = l15 * 64 + (slot << 3) + (lg & 1) * 4;
      *(u16x4*)&Plw[addr] = pk;
    }
    if (cls == 1) {
      if (kt == qt - 1) {
#pragma unroll
        for (int ni = 0; ni < 4; ++ni) pks0[ni] = pcur[ni];
        mu0 = mrow;
      } else if (kt == qt) {
#pragma unroll
        for (int ni = 0; ni < 4; ++ni) pks1[ni] = pcur[ni];
        mu1 = mrow;
      } else {
#pragma unroll
        for (int ni = 0; ni < 4; ++ni) pks2[ni] = pcur[ni];
        mu2 = mrow;
      }
    }

    // O += P * V  (Pl same-wave dep; V fragments already in regs)
#pragma unroll
    for (int ks = 0; ks < 2; ++ks) {
      bf16x8 pf = *(const bf16x8*)&Plw[l15 * 64 + (((ks * 4 + lg) ^ (l15 & 7)) << 3)];
#pragma unroll
      for (int nd = 0; nd < 4; ++nd)
        O[nd] = __builtin_amdgcn_mfma_f32_16x16x32_bf16(pf, vg[ks][nd], O[nd], 0, 0, 0);
    }
    __syncthreads();
  }

  // ---- epilogue: build unnormalized T row in LDS (over dead K/Pl), out2 MFMA ----
  unsigned short* Tl16 = (unsigned short*)smem + w * (16 * T_STR);
  {
    u16x4 z4 = {0, 0, 0, 0};
    u16x4* tl4 = (u16x4*)Tl16;
    for (int i = l; i < 16 * T_STR / 4; i += 64) tl4[i] = z4;
  }
  float bandsum = 0.f;
  auto addband = [&](const u16x4* pk, float muv, int btc) {
    float scale = __builtin_amdgcn_exp2f(muv - mrow);   // 0 for invalid tiles
    int jbase = (qt + btc - 1) * 64 + lg * 4 - q_lane + 64;
#pragma unroll
    for (int ni = 0; ni < 4; ++ni)
#pragma unroll
      for (int r = 0; r < 4; ++r) {
        int j = jbase + ni * 16 + r;
        if (j >= 1 && j <= 127) {
          float pf = bf2f((unsigned short)pk[ni][r]) * scale;
          Tl16[l15 * T_STR + j] = f2bfrn(pf);
          bandsum += pf;
        }
      }
  };
  addband(pks0, mu0, 0);
  addband(pks1, mu1, 1);
  addband(pks2, mu2, 2);
  bandsum += __shfl_xor(bandsum, 16);
  bandsum += __shfl_xor(bandsum, 32);
  if (lg == 0) {
    Tl16[l15 * T_STR] = f2bfrn(t0row);
    Tl16[l15 * T_STR + 128] = f2bfrn(fmaxf(0.f, lrow - t0row - bandsum));
  }
  // O += T @ EvT  (A = T from LDS, B = EvTp from global/L2; same C layout)
#pragma unroll
  for (int ks6 = 0; ks6 < 6; ++ks6) {
    bf16x8 af = *(const bf16x8*)(Tl16 + l15 * T_STR + ks6 * 32 + lg * 8);
    bf16x8 bfr[4];
#pragma unroll
    for (int nd = 0; nd < 4; ++nd)
      bfr[nd] = *(const bf16x8*)(EvTp + (size_t)(nd * 16 + l15) * EV_LD + ks6 * 32 + lg * 8);
#pragma unroll
    for (int nd = 0; nd < 4; ++nd)
      O[nd] = __builtin_amdgcn_mfma_f32_16x16x32_bf16(af, bfr[nd], O[nd], 0, 0, 0);
  }

  // normalize + store (out1 + out2)
  float invl = 1.f / lrow;
  float iq[4];
#pragma unroll
  for (int r = 0; r < 4; ++r) iq[r] = __shfl(invl, lg * 4 + r);
#pragma unroll
  for (int r = 0; r < 4; ++r) {
    size_t rowi = (size_t)(rowbase + (lg * 4 + r) * H_);
#pragma unroll
    for (int nd = 0; nd < 4; ++nd)
      tmp[rowi * HD_ + nd * 16 + l15] = f2bfrn(O[nd][r] * iq[r]);
  }
}

// ---------------------------------------------------------------------------
extern "C" void kernel_launch(void* const* d_in, const int* in_sizes, int n_in,
                              void* d_out, int out_size, void* d_ws, size_t ws_size,
                              hipStream_t stream) {
  (void)in_sizes; (void)n_in; (void)out_size; (void)ws_size;
  const float* q  = (const float*)d_in[0];
  const float* k  = (const float*)d_in[1];
  const float* v  = (const float*)d_in[2];
  const float* Wq = (const float*)d_in[3];
  const float* bq = (const float*)d_in[4];
  const float* Wk = (const float*)d_in[5];
  const float* bk = (const float*)d_in[6];
  const float* Wv = (const float*)d_in[7];
  const float* bv = (const float*)d_in[8];
  const float* Wo = (const float*)d_in[9];
  const float* bo = (const float*)d_in[10];
  const float* Ek = (const float*)d_in[11];
  const float* Ev = (const float*)d_in[12];

  char* ws = (char*)d_ws;
  constexpr size_t SZ_QKV = (size_t)B_ * L_ * D_ * 2;           // 8 MB
  constexpr size_t SZ_W   = (size_t)D_ * D_ * 2;                // 2 MB
  constexpr size_t OFF_QB = 0;
  constexpr size_t OFF_KB = OFF_QB + SZ_QKV;
  constexpr size_t OFF_VB = OFF_KB + SZ_QKV;
  constexpr size_t OFF_WQ = OFF_VB + SZ_QKV;
  constexpr size_t OFF_WK = OFF_WQ + SZ_W;
  constexpr size_t OFF_WV = OFF_WK + SZ_W;
  constexpr size_t OFF_WO = OFF_WV + SZ_W;
  constexpr size_t OFF_EKP = OFF_WO + SZ_W;                     // 256*64*2
  constexpr size_t OFF_EVT = OFF_EKP + 256 * 64 * 2;            // 128*192*2
  constexpr size_t OFF_QE = OFF_EVT + 128 * EV_LD * 2;          // NROW*132*2
  constexpr size_t OFF_QP = OFF_QE + (size_t)NROW * QE_LD * 2;
  constexpr size_t OFF_KP = OFF_QP + SZ_QKV;
  constexpr size_t OFF_VPT = OFF_KP + SZ_QKV;
  constexpr size_t OFF_TMP = OFF_VPT + SZ_QKV;                  // NROW*64*2

  auto U16 = [&](size_t off) { return (unsigned short*)(ws + off); };

  // all f32->bf16 converts + Ek/Ev padding in ONE dispatch
  {
    ConvArgs c{};
    c.s[0] = q;  c.d[0] = U16(OFF_QB); c.n4[0] = (B_ * L_ * D_) / 4;
    c.s[1] = k;  c.d[1] = U16(OFF_KB); c.n4[1] = (B_ * L_ * D_) / 4;
    c.s[2] = v;  c.d[2] = U16(OFF_VB); c.n4[2] = (B_ * L_ * D_) / 4;
    c.s[3] = Wq; c.d[3] = U16(OFF_WQ); c.n4[3] = (D_ * D_) / 4;
    c.s[4] = Wk; c.d[4] = U16(OFF_WK); c.n4[4] = (D_ * D_) / 4;
    c.s[5] = Wv; c.d[5] = U16(OFF_WV); c.n4[5] = (D_ * D_) / 4;
    c.s[6] = Wo; c.d[6] = U16(OFF_WO); c.n4[6] = (D_ * D_) / 4;
    c.ek = Ek; c.ev = Ev; c.ekp = U16(OFF_EKP); c.evtp = U16(OFF_EVT);
    f32_to_bf16_multi<<<dim3(1024, 8), 256, 0, stream>>>(c);
  }

  // projections qp/kp/vpT = X @ W^T + b, z-batched, 128x128 tiles (MI=4).
  // z==2 (V) writes vpT transposed directly -- no separate transpose pass.
  {
    Gemm3 g{};
    g.A[0] = U16(OFF_QB); g.Bt[0] = U16(OFF_WQ); g.bias[0] = bq; g.C[0] = U16(OFF_QP);
    g.A[1] = U16(OFF_KB); g.Bt[1] = U16(OFF_WK); g.bias[1] = bk; g.C[1] = U16(OFF_KP);
    g.A[2] = U16(OFF_VB); g.Bt[2] = U16(OFF_WV); g.bias[2] = bv; g.C[2] = U16(OFF_VPT);
    gemm_bt<4, true, true, true><<<dim3(32, 8, 3), 256, 0, stream>>>(
        g, 1024, 1024, 1024, 1024, 32);
  }

  // qE = qp @ Ek^T cols 0..127 only (col 128 filled by flash prologue)
  {
    Gemm3 g{};
    g.A[0] = U16(OFF_QP); g.Bt[0] = U16(OFF_EKP); g.bias[0] = nullptr; g.C[0] = U16(OFF_QE);
    gemm_bt<2, true, false, false><<<dim3(1024, 1, 1), 256, 0, stream>>>(
        g, 64, 64, QE_LD, 128, 2);
  }

  // fused attention (+ full out2 in epilogue)
  flash_fwd_k<<<1024, 256, 0, stream>>>(
      U16(OFF_QP), U16(OFF_KP), U16(OFF_VPT), U16(OFF_QE),
      U16(OFF_EKP), U16(OFF_EVT), U16(OFF_TMP));

  // out = tmp @ Wo^T + bo  (f32 out), 64-row tiles -> 512 blocks
  {
    Gemm3 g{};
    g.A[0] = U16(OFF_TMP); g.Bt[0] = U16(OFF_WO); g.bias[0] = bo; g.C[0] = d_out;
    gemm_bt<2, false, true, false><<<dim3(64, 8, 1), 256, 0, stream>>>(
        g, 1024, 1024, 1024, 1024, 32);
  }
}

// Round 18
// 133.958 us; speedup vs baseline: 1.3111x; 1.3111x over previous
//
#include <hip/hip_runtime.h>
#include <hip/hip_bf16.h>
#include <stdint.h>
#include <stddef.h>

#define B_ 4
#define L_ 1024
#define D_ 1024
#define H_ 16
#define HD_ 64
#define NROW 65536      // B*L*H
#define QE_LD 132       // qE row stride (bf16 elems); cols 0..127 from GEMM, 128 from flash prologue
#define EV_LD 192       // EvT row stride (= out2 MFMA K, 6 k-tiles of 32)
#define T_STR 200       // epilogue T row stride in LDS (u16; pad kills conflicts)

typedef __attribute__((ext_vector_type(8))) short bf16x8;
typedef __attribute__((ext_vector_type(4))) float f32x4;
typedef __attribute__((ext_vector_type(4))) unsigned short u16x4;

__device__ __forceinline__ float bf2f(unsigned short u) {
  union { unsigned int i; float f; } v; v.i = ((unsigned int)u) << 16; return v.f;
}
__device__ __forceinline__ unsigned short f2bf(float f) {
  union { float f; unsigned int i; } v; v.f = f;
  return (unsigned short)((v.i + 0x7fffu + ((v.i >> 16) & 1u)) >> 16);
}
__device__ __forceinline__ unsigned short f2bfrn(float f) {
  __hip_bfloat16 h = __float2bfloat16(f);
  return *reinterpret_cast<unsigned short*>(&h);
}
__device__ __forceinline__ void async16(const void* g, void* l) {
  __builtin_amdgcn_global_load_lds(
      (const __attribute__((address_space(1))) unsigned int*)g,
      (__attribute__((address_space(3))) unsigned int*)l, 16, 0, 0);
}

// ---------------------------------------------------------------------------
// f32 -> bf16 convert, 7 tensors + Ek/Ev padding, one dispatch
// ---------------------------------------------------------------------------
struct ConvArgs {
  const float* s[7]; unsigned short* d[7]; int n4[7];
  const float* ek; const float* ev;
  unsigned short* ekp; unsigned short* evtp;
};

__global__ __launch_bounds__(256) void f32_to_bf16_multi(ConvArgs a) {
  const int y = blockIdx.y;
  if (y == 7) {
    int i = blockIdx.x * 256 + threadIdx.x;
    if (i < 256 * 64) {
      int r = i >> 6, dd = i & 63;
      a.ekp[i] = (r < 129) ? f2bf(a.ek[r * 64 + dd]) : (unsigned short)0;
    }
    if (i < 128 * EV_LD) {
      int dd = i / EV_LD, r = i - dd * EV_LD;
      a.evtp[i] = (dd < 64 && r < 129) ? f2bf(a.ev[r * 64 + dd]) : (unsigned short)0;
    }
    return;
  }
  const float* s = a.s[y];
  unsigned short* d = a.d[y];
  const int n4 = a.n4[y];
  int i = blockIdx.x * 256 + threadIdx.x;
  int stride = gridDim.x * 256;
  for (; i < n4; i += stride) {
    float4 v = ((const float4*)s)[i];
    u16x4 o;
    o[0] = f2bf(v.x); o[1] = f2bf(v.y); o[2] = f2bf(v.z); o[3] = f2bf(v.w);
    ((u16x4*)d)[i] = o;
  }
}

// ---------------------------------------------------------------------------
// GEMM: C[M,N] = A[M,K] * Bt[N,K]^T (+bias) ; bf16 in, f32 acc.
// Tile (MI*32)x128, BK=32, 4 waves, chunk-swizzled LDS, global_load_lds x16.
// z-batched (blockIdx.z selects pointer set). VPT: for z==2 the epilogue
// writes C transposed as vpT (B,H,HD,L) directly.
// ---------------------------------------------------------------------------
struct Gemm3 {
  const unsigned short* A[3];
  const unsigned short* Bt[3];
  const float* bias[3];
  void* C[3];
};

template<int MI, bool OBF16, bool BIAS, bool VPT>
__global__ __launch_bounds__(256, 8 / MI) void gemm_bt(Gemm3 ga, int lda, int ldb, int ldc,
                                                       int Ncut, int ktiles) {
  constexpr int BM = MI * 32;
  __shared__ unsigned short Al[2][BM * 32];
  __shared__ unsigned short Bl[2][128 * 32];
  const unsigned short* A = ga.A[blockIdx.z];
  const unsigned short* Bt = ga.Bt[blockIdx.z];
  const float* bias = ga.bias[blockIdx.z];
  void* Cv = ga.C[blockIdx.z];
  const int tid = threadIdx.x;
  const int w = tid >> 6, l = tid & 63;
  const int l15 = l & 15, lg = l >> 4;
  const int row0 = blockIdx.x * BM, col0 = blockIdx.y * 128;
  const int wm = (w >> 1) * (MI * 16), wn = (w & 1) * 64;

  f32x4 acc[MI][4];
#pragma unroll
  for (int i = 0; i < MI; ++i)
#pragma unroll
    for (int j = 0; j < 4; ++j) acc[i][j] = {0.f, 0.f, 0.f, 0.f};

  auto stage = [&](int buf, int kt) {
#pragma unroll
    for (int i = 0; i < MI / 2; ++i) {
      int p = (i * 4 + w) * 1024 + l * 16;   // byte offset within A tile
      int m = p >> 6;                        // tile-local row (64B rows)
      int clog = (l & 3) ^ ((m >> 1) & 3);   // logical k-chunk for this slot
      async16(A + (size_t)(row0 + m) * lda + kt * 32 + clog * 8,
              (char*)&Al[buf][0] + (i * 4 + w) * 1024);
    }
#pragma unroll
    for (int i = 0; i < 2; ++i) {
      int p = (i * 4 + w) * 1024 + l * 16;
      int m = p >> 6;
      int clog = (l & 3) ^ ((m >> 1) & 3);
      async16(Bt + (size_t)(col0 + m) * ldb + kt * 32 + clog * 8,
              (char*)&Bl[buf][0] + (i * 4 + w) * 1024);
    }
  };

  stage(0, 0);
  __syncthreads();
  for (int kt = 0; kt < ktiles; ++kt) {
    int cur = kt & 1;
    if (kt + 1 < ktiles) stage(cur ^ 1, kt + 1);
    bf16x8 af[MI], bfr[4];
#pragma unroll
    for (int mi = 0; mi < MI; ++mi) {
      int m = wm + mi * 16 + l15;
      af[mi] = *(const bf16x8*)&Al[cur][m * 32 + ((lg ^ ((m >> 1) & 3)) << 3)];
    }
#pragma unroll
    for (int ni = 0; ni < 4; ++ni) {
      int n = wn + ni * 16 + l15;
      bfr[ni] = *(const bf16x8*)&Bl[cur][n * 32 + ((lg ^ ((n >> 1) & 3)) << 3)];
    }
#pragma unroll
    for (int mi = 0; mi < MI; ++mi)
#pragma unroll
      for (int ni = 0; ni < 4; ++ni)
        acc[mi][ni] = __builtin_amdgcn_mfma_f32_16x16x32_bf16(af[mi], bfr[ni], acc[mi][ni], 0, 0, 0);
    __syncthreads();
  }

  if (VPT && blockIdx.z == 2) {
    // write C transposed: col -> (h,d), row -> (b,l); 4 rows = contiguous u16x4
    unsigned short* vpT = (unsigned short*)Cv;
#pragma unroll
    for (int ni = 0; ni < 4; ++ni) {
      int col = col0 + wn + ni * 16 + l15;
      float bv = BIAS ? bias[col] : 0.f;
#pragma unroll
      for (int mi = 0; mi < MI; ++mi) {
        int rowb = row0 + wm + mi * 16 + lg * 4;
        int bb = rowb >> 10, lrow = rowb & 1023;
        u16x4 o;
#pragma unroll
        for (int r = 0; r < 4; ++r) o[r] = f2bf(acc[mi][ni][r] + bv);
        *(u16x4*)(vpT + ((size_t)((bb * H_ + (col >> 6)) * HD_ + (col & 63))) * L_ + lrow) = o;
      }
    }
    return;
  }

#pragma unroll
  for (int ni = 0; ni < 4; ++ni) {
    int col = col0 + wn + ni * 16 + l15;
    if (col < Ncut) {
      float bv = BIAS ? bias[col] : 0.f;
#pragma unroll
      for (int mi = 0; mi < MI; ++mi) {
        int rowb = row0 + wm + mi * 16 + lg * 4;
#pragma unroll
        for (int r = 0; r < 4; ++r) {
          float v = acc[mi][ni][r] + bv;
          size_t off = (size_t)(rowb + r) * ldc + col;
          if (OBF16) ((unsigned short*)Cv)[off] = f2bf(v);
          else       ((float*)Cv)[off] = v;
        }
      }
    }
  }
}

// ---------------------------------------------------------------------------
// Fused flash attention + relative logits + FULL out2 (T @ EvT) in epilogue.
// Swapped QK^T (lane owns q-row), log2-domain softmax, defer-max THR=8.
// K and V staged in LDS via global_load_lds (coalesced contiguous rows; the
// R16 direct-V experiment showed per-lane fragment loads are 16-way
// uncoalesced: 59->101us). qe128 computed in prologue, stored to qerow[128]
// so the band gather stays an unconditional clamp-indexed load [0..128].
// No s_setprio (neutral: lockstep waves, R10).
// Grid: 1024 linear blocks, bh = bid&63 (XCD locality), qt = bid>>6.
// ---------------------------------------------------------------------------
__global__ __launch_bounds__(256, 3) void flash_fwd_k(
    const unsigned short* __restrict__ qp, const unsigned short* __restrict__ kp,
    const unsigned short* __restrict__ vpT, unsigned short* __restrict__ qE,
    const unsigned short* __restrict__ Ekp, const unsigned short* __restrict__ EvTp,
    unsigned short* __restrict__ tmp) {
  __shared__ __align__(16) char smem[40960];
  unsigned short (*Kl)[4096] = (unsigned short (*)[4096])smem;
  unsigned short (*Vl)[4096] = (unsigned short (*)[4096])(smem + 16384);
  const int tid = threadIdx.x, w = tid >> 6, l = tid & 63;
  unsigned short* Plw = (unsigned short*)(smem + 32768) + w * 1024;
  const int l15 = l & 15, lg = l >> 4;
  const int bid = blockIdx.x;
  const int bh = bid & 63, qt = bid >> 6;
  const int b = bh >> 4, h = bh & 15;
  const int qw = qt * 64 + w * 16;
  const int q_lane = qw + l15;                 // this lane's q row
  const int rowbase = (b * L_ + qw) * H_ + h;
  const int rowi_lane = rowbase + l15 * H_;
  constexpr float C1 = 0.125f * 1.44269504f;   // scale * log2(e)

  // Q fragments (B-operand): col = q = qw + l15, d-chunk = ks*32 + lg*8
  bf16x8 qf[2];
  {
    const unsigned short* qrp = qp + (size_t)rowi_lane * HD_;
#pragma unroll
    for (int ks = 0; ks < 2; ++ks) qf[ks] = *(const bf16x8*)(qrp + ks * 32 + lg * 8);
  }
  unsigned short* qerow = qE + (size_t)rowi_lane * QE_LD;
  const float qe0L = bf2f(qerow[0]) * C1;
  // qe128 = qp[row] . Ek[128] : per-lane 16-elem partial + xor16/xor32 reduce.
  // Store raw dot to qerow[128] so the clamp-gather can read it unconditionally.
  float qe128L;
  {
    const unsigned short* ek128 = Ekp + 128 * 64;
    float dot = 0.f;
#pragma unroll
    for (int ks = 0; ks < 2; ++ks) {
      const unsigned short* ep = ek128 + ks * 32 + lg * 8;
#pragma unroll
      for (int e = 0; e < 8; ++e)
        dot += bf2f((unsigned short)qf[ks][e]) * bf2f(ep[e]);
    }
    dot += __shfl_xor(dot, 16);
    dot += __shfl_xor(dot, 32);
    qerow[128] = f2bf(dot);      // same-thread store; read later by this lane only
    qe128L = dot * C1;
  }

  f32x4 O[4];
#pragma unroll
  for (int nd = 0; nd < 4; ++nd) O[nd] = {0.f, 0.f, 0.f, 0.f};
  float mrow = -1e30f, lrow = 0.f, t0row = 0.f;   // mrow in log2-units

  // band state (static-indexed register arrays)
  u16x4 pks0[4], pks1[4], pks2[4];
  float mu0 = -1e30f, mu1 = -1e30f, mu2 = -1e30f;
  {
    u16x4 z4 = {0, 0, 0, 0};
#pragma unroll
    for (int ni = 0; ni < 4; ++ni) { pks0[ni] = z4; pks1[ni] = z4; pks2[ni] = z4; }
  }

  auto stage = [&](int buf, int kt) {
#pragma unroll
    for (int i = 0; i < 2; ++i) {
      int p = (i * 4 + w) * 1024 + l * 16;  // byte in 8KB tile (rows = 128B)
      int row = p >> 7;
      int clog = (l & 7) ^ (row & 7);
      async16(kp + ((size_t)((b * L_ + kt * 64 + row) * H_ + h)) * HD_ + clog * 8,
              (char*)&Kl[buf][0] + (i * 4 + w) * 1024);
      async16(vpT + ((size_t)((b * H_ + h) * HD_ + row)) * L_ + kt * 64 + clog * 8,
              (char*)&Vl[buf][0] + (i * 4 + w) * 1024);
    }
  };

  stage(0, 0);
  __syncthreads();

  for (int kt = 0; kt < 16; ++kt) {
    int cur = kt & 1;
    if (kt + 1 < 16) stage(cur ^ 1, kt + 1);

    // S^T = K * Q^T: lane col = q (l15), rows = k-local (ni*16 + lg*4 + r)
    f32x4 S[4];
#pragma unroll
    for (int ni = 0; ni < 4; ++ni) S[ni] = {0.f, 0.f, 0.f, 0.f};
#pragma unroll
    for (int ks = 0; ks < 2; ++ks) {
      bf16x8 kf[4];
#pragma unroll
      for (int ni = 0; ni < 4; ++ni) {
        int kk = ni * 16 + l15;
        kf[ni] = *(const bf16x8*)&Kl[cur][kk * 64 + (((ks * 4 + lg) ^ (kk & 7)) << 3)];
      }
#pragma unroll
      for (int ni = 0; ni < 4; ++ni)
        S[ni] = __builtin_amdgcn_mfma_f32_16x16x32_bf16(kf[ni], qf[ks], S[ni], 0, 0, 0);
    }

    const int cls = (kt <= qt - 2) ? 0 : ((kt >= qt + 2) ? 2 : 1);
    const int based = kt * 64 - q_lane;

    // logits in log2 domain (band: unconditional clamp-indexed gather [0..128])
    if (cls == 1) {
#pragma unroll
      for (int ni = 0; ni < 4; ++ni)
#pragma unroll
        for (int r = 0; r < 4; ++r) {
          int delta = based + ni * 16 + lg * 4 + r;
          int idx = min(max(delta, -64), 64) + 64;
          S[ni][r] = S[ni][r] * C1 + bf2f(qerow[idx]) * C1;
        }
    } else {
      float qeL = (cls == 0) ? qe0L : qe128L;
#pragma unroll
      for (int ni = 0; ni < 4; ++ni)
#pragma unroll
        for (int r = 0; r < 4; ++r) S[ni][r] = S[ni][r] * C1 + qeL;
    }

    // row max: reg tree + 2 shuffles
    float x0 = fmaxf(fmaxf(S[0][0], S[0][1]), fmaxf(S[0][2], S[0][3]));
    float x1 = fmaxf(fmaxf(S[1][0], S[1][1]), fmaxf(S[1][2], S[1][3]));
    float x2 = fmaxf(fmaxf(S[2][0], S[2][1]), fmaxf(S[2][2], S[2][3]));
    float x3 = fmaxf(fmaxf(S[3][0], S[3][1]), fmaxf(S[3][2], S[3][3]));
    float pmax = fmaxf(fmaxf(x0, x1), fmaxf(x2, x3));
    pmax = fmaxf(pmax, __shfl_xor(pmax, 16));
    pmax = fmaxf(pmax, __shfl_xor(pmax, 32));

    // defer-max (THR = 8 nats = 11.54 log2-units)
    float a = 1.f;
    if (!__all(pmax <= mrow + 11.54f)) {
      float mnew = fmaxf(mrow, pmax);
      a = __builtin_amdgcn_exp2f(mrow - mnew);
      mrow = mnew;
      float aq0 = __shfl(a, lg * 4 + 0);
      float aq1 = __shfl(a, lg * 4 + 1);
      float aq2 = __shfl(a, lg * 4 + 2);
      float aq3 = __shfl(a, lg * 4 + 3);
#pragma unroll
      for (int nd = 0; nd < 4; ++nd) {
        O[nd][0] *= aq0; O[nd][1] *= aq1; O[nd][2] *= aq2; O[nd][3] *= aq3;
      }
    }

    // p = exp2(sL - mL)
#pragma unroll
    for (int ni = 0; ni < 4; ++ni)
#pragma unroll
      for (int r = 0; r < 4; ++r)
        S[ni][r] = __builtin_amdgcn_exp2f(S[ni][r] - mrow);

    float s0 = (S[0][0] + S[0][1]) + (S[0][2] + S[0][3]);
    float s1 = (S[1][0] + S[1][1]) + (S[1][2] + S[1][3]);
    float s2 = (S[2][0] + S[2][1]) + (S[2][2] + S[2][3]);
    float s3 = (S[3][0] + S[3][1]) + (S[3][2] + S[3][3]);
    float ps = (s0 + s1) + (s2 + s3);
    ps += __shfl_xor(ps, 16);
    ps += __shfl_xor(ps, 32);
    lrow = lrow * a + ps;

    if (cls == 0) {
      t0row = t0row * a + ps;
    } else if (cls == 2) {
      t0row = t0row * a;
    } else if (kt == qt - 1) {
      float p0 = 0.f;
#pragma unroll
      for (int ni = 0; ni < 4; ++ni)
#pragma unroll
        for (int r = 0; r < 4; ++r)
          if (based + ni * 16 + lg * 4 + r <= -64) p0 += S[ni][r];
      p0 += __shfl_xor(p0, 16);
      p0 += __shfl_xor(p0, 32);
      t0row = t0row * a + p0;
    } else {
      t0row = t0row * a;
    }

    // pack p to bf16; write Pl (per-wave, swizzled); save band tiles to regs
    u16x4 pcur[4];
#pragma unroll
    for (int ni = 0; ni < 4; ++ni) {
      u16x4 pk;
#pragma unroll
      for (int r = 0; r < 4; ++r) pk[r] = f2bfrn(S[ni][r]);
      pcur[ni] = pk;
      int slot = (ni * 2 + (lg >> 1)) ^ (l15 & 7);
      int addr = l15 * 64 + (slot << 3) + (lg & 1) * 4;
      *(u16x4*)&Plw[addr] = pk;
    }
    if (cls == 1) {
      if (kt == qt - 1) {
#pragma unroll
        for (int ni = 0; ni < 4; ++ni) pks0[ni] = pcur[ni];
        mu0 = mrow;
      } else if (kt == qt) {
#pragma unroll
        for (int ni = 0; ni < 4; ++ni) pks1[ni] = pcur[ni];
        mu1 = mrow;
      } else {
#pragma unroll
        for (int ni = 0; ni < 4; ++ni) pks2[ni] = pcur[ni];
        mu2 = mrow;
      }
    }

    // O += P * V  (Pl same-wave dep; Vl from barrier)
#pragma unroll
    for (int ks = 0; ks < 2; ++ks) {
      bf16x8 pf = *(const bf16x8*)&Plw[l15 * 64 + (((ks * 4 + lg) ^ (l15 & 7)) << 3)];
      bf16x8 vf[4];
#pragma unroll
      for (int nd = 0; nd < 4; ++nd) {
        int d = nd * 16 + l15;
        vf[nd] = *(const bf16x8*)&Vl[cur][d * 64 + (((ks * 4 + lg) ^ (d & 7)) << 3)];
      }
#pragma unroll
      for (int nd = 0; nd < 4; ++nd)
        O[nd] = __builtin_amdgcn_mfma_f32_16x16x32_bf16(pf, vf[nd], O[nd], 0, 0, 0);
    }
    __syncthreads();
  }

  // ---- epilogue: build unnormalized T row in LDS (over dead K/V), out2 MFMA ----
  unsigned short* Tl16 = (unsigned short*)smem + w * (16 * T_STR);
  {
    u16x4 z4 = {0, 0, 0, 0};
    u16x4* tl4 = (u16x4*)Tl16;
    for (int i = l; i < 16 * T_STR / 4; i += 64) tl4[i] = z4;
  }
  float bandsum = 0.f;
  auto addband = [&](const u16x4* pk, float muv, int btc) {
    float scale = __builtin_amdgcn_exp2f(muv - mrow);   // 0 for invalid tiles
    int jbase = (qt + btc - 1) * 64 + lg * 4 - q_lane + 64;
#pragma unroll
    for (int ni = 0; ni < 4; ++ni)
#pragma unroll
      for (int r = 0; r < 4; ++r) {
        int j = jbase + ni * 16 + r;
        if (j >= 1 && j <= 127) {
          float pf = bf2f((unsigned short)pk[ni][r]) * scale;
          Tl16[l15 * T_STR + j] = f2bfrn(pf);
          bandsum += pf;
        }
      }
  };
  addband(pks0, mu0, 0);
  addband(pks1, mu1, 1);
  addband(pks2, mu2, 2);
  bandsum += __shfl_xor(bandsum, 16);
  bandsum += __shfl_xor(bandsum, 32);
  if (lg == 0) {
    Tl16[l15 * T_STR] = f2bfrn(t0row);
    Tl16[l15 * T_STR + 128] = f2bfrn(fmaxf(0.f, lrow - t0row - bandsum));
  }
  // O += T @ EvT  (A = T from LDS, B = EvTp from global/L2; same C layout)
#pragma unroll
  for (int ks6 = 0; ks6 < 6; ++ks6) {
    bf16x8 af = *(const bf16x8*)(Tl16 + l15 * T_STR + ks6 * 32 + lg * 8);
    bf16x8 bfr[4];
#pragma unroll
    for (int nd = 0; nd < 4; ++nd)
      bfr[nd] = *(const bf16x8*)(EvTp + (size_t)(nd * 16 + l15) * EV_LD + ks6 * 32 + lg * 8);
#pragma unroll
    for (int nd = 0; nd < 4; ++nd)
      O[nd] = __builtin_amdgcn_mfma_f32_16x16x32_bf16(af, bfr[nd], O[nd], 0, 0, 0);
  }

  // normalize + store (out1 + out2)
  float invl = 1.f / lrow;
  float iq[4];
#pragma unroll
  for (int r = 0; r < 4; ++r) iq[r] = __shfl(invl, lg * 4 + r);
#pragma unroll
  for (int r = 0; r < 4; ++r) {
    size_t rowi = (size_t)(rowbase + (lg * 4 + r) * H_);
#pragma unroll
    for (int nd = 0; nd < 4; ++nd)
      tmp[rowi * HD_ + nd * 16 + l15] = f2bfrn(O[nd][r] * iq[r]);
  }
}

// ---------------------------------------------------------------------------
extern "C" void kernel_launch(void* const* d_in, const int* in_sizes, int n_in,
                              void* d_out, int out_size, void* d_ws, size_t ws_size,
                              hipStream_t stream) {
  (void)in_sizes; (void)n_in; (void)out_size; (void)ws_size;
  const float* q  = (const float*)d_in[0];
  const float* k  = (const float*)d_in[1];
  const float* v  = (const float*)d_in[2];
  const float* Wq = (const float*)d_in[3];
  const float* bq = (const float*)d_in[4];
  const float* Wk = (const float*)d_in[5];
  const float* bk = (const float*)d_in[6];
  const float* Wv = (const float*)d_in[7];
  const float* bv = (const float*)d_in[8];
  const float* Wo = (const float*)d_in[9];
  const float* bo = (const float*)d_in[10];
  const float* Ek = (const float*)d_in[11];
  const float* Ev = (const float*)d_in[12];

  char* ws = (char*)d_ws;
  constexpr size_t SZ_QKV = (size_t)B_ * L_ * D_ * 2;           // 8 MB
  constexpr size_t SZ_W   = (size_t)D_ * D_ * 2;                // 2 MB
  constexpr size_t OFF_QB = 0;
  constexpr size_t OFF_KB = OFF_QB + SZ_QKV;
  constexpr size_t OFF_VB = OFF_KB + SZ_QKV;
  constexpr size_t OFF_WQ = OFF_VB + SZ_QKV;
  constexpr size_t OFF_WK = OFF_WQ + SZ_W;
  constexpr size_t OFF_WV = OFF_WK + SZ_W;
  constexpr size_t OFF_WO = OFF_WV + SZ_W;
  constexpr size_t OFF_EKP = OFF_WO + SZ_W;                     // 256*64*2
  constexpr size_t OFF_EVT = OFF_EKP + 256 * 64 * 2;            // 128*192*2
  constexpr size_t OFF_QE = OFF_EVT + 128 * EV_LD * 2;          // NROW*132*2
  constexpr size_t OFF_QP = OFF_QE + (size_t)NROW * QE_LD * 2;
  constexpr size_t OFF_KP = OFF_QP + SZ_QKV;
  constexpr size_t OFF_VPT = OFF_KP + SZ_QKV;
  constexpr size_t OFF_TMP = OFF_VPT + SZ_QKV;                  // NROW*64*2

  auto U16 = [&](size_t off) { return (unsigned short*)(ws + off); };

  // all f32->bf16 converts + Ek/Ev padding in ONE dispatch
  {
    ConvArgs c{};
    c.s[0] = q;  c.d[0] = U16(OFF_QB); c.n4[0] = (B_ * L_ * D_) / 4;
    c.s[1] = k;  c.d[1] = U16(OFF_KB); c.n4[1] = (B_ * L_ * D_) / 4;
    c.s[2] = v;  c.d[2] = U16(OFF_VB); c.n4[2] = (B_ * L_ * D_) / 4;
    c.s[3] = Wq; c.d[3] = U16(OFF_WQ); c.n4[3] = (D_ * D_) / 4;
    c.s[4] = Wk; c.d[4] = U16(OFF_WK); c.n4[4] = (D_ * D_) / 4;
    c.s[5] = Wv; c.d[5] = U16(OFF_WV); c.n4[5] = (D_ * D_) / 4;
    c.s[6] = Wo; c.d[6] = U16(OFF_WO); c.n4[6] = (D_ * D_) / 4;
    c.ek = Ek; c.ev = Ev; c.ekp = U16(OFF_EKP); c.evtp = U16(OFF_EVT);
    f32_to_bf16_multi<<<dim3(1024, 8), 256, 0, stream>>>(c);
  }

  // projections qp/kp/vpT = X @ W^T + b, z-batched, 128x128 tiles (MI=4).
  // z==2 (V) writes vpT transposed directly -- no separate transpose pass.
  {
    Gemm3 g{};
    g.A[0] = U16(OFF_QB); g.Bt[0] = U16(OFF_WQ); g.bias[0] = bq; g.C[0] = U16(OFF_QP);
    g.A[1] = U16(OFF_KB); g.Bt[1] = U16(OFF_WK); g.bias[1] = bk; g.C[1] = U16(OFF_KP);
    g.A[2] = U16(OFF_VB); g.Bt[2] = U16(OFF_WV); g.bias[2] = bv; g.C[2] = U16(OFF_VPT);
    gemm_bt<4, true, true, true><<<dim3(32, 8, 3), 256, 0, stream>>>(
        g, 1024, 1024, 1024, 1024, 32);
  }

  // qE = qp @ Ek^T cols 0..127 only (col 128 filled by flash prologue)
  {
    Gemm3 g{};
    g.A[0] = U16(OFF_QP); g.Bt[0] = U16(OFF_EKP); g.bias[0] = nullptr; g.C[0] = U16(OFF_QE);
    gemm_bt<2, true, false, false><<<dim3(1024, 1, 1), 256, 0, stream>>>(
        g, 64, 64, QE_LD, 128, 2);
  }

  // fused attention (+ full out2 in epilogue)
  flash_fwd_k<<<1024, 256, 0, stream>>>(
      U16(OFF_QP), U16(OFF_KP), U16(OFF_VPT), U16(OFF_QE),
      U16(OFF_EKP), U16(OFF_EVT), U16(OFF_TMP));

  // out = tmp @ Wo^T + bo  (f32 out), 64-row tiles -> 512 blocks
  {
    Gemm3 g{};
    g.A[0] = U16(OFF_TMP); g.Bt[0] = U16(OFF_WO); g.bias[0] = bo; g.C[0] = d_out;
    gemm_bt<2, false, true, false><<<dim3(64, 8, 1), 256, 0, stream>>>(
        g, 1024, 1024, 1024, 1024, 32);
  }
}